// Round 4
// baseline (733.972 us; speedup 1.0000x reference)
//
#include <hip/hip_runtime.h>
#include <math.h>

#define NB 256       // batch
#define HT 17
#define WT 17
#define HI 384
#define WI 384
#define LH 368
#define LW 368
#define NTEMPL 289   // HT*WT
#define TPAD 20      // padded template row width (float4-friendly)
#define TY 32        // output tile rows per block
#define TX 128       // output tile cols per block
#define NTXT 3       // x tiles (3*128 = 384)
#define NTYT 12      // y tiles (12*32 = 384)
#define NTILES 36    // tiles per batch
#define BR 48        // bg tile rows (TY + 16)
#define BP 144       // bg/cb pitch: exactly 128+16 used. All wave LDS accesses are
                     // within-row 16-lane-contiguous -> pitch-independent conflict-free.
#define TEMP_INV 25.0f
#define EPSV 1e-6f

// ---------------- kernel 1: per-batch template normalization ----------------
__global__ __launch_bounds__(256) void tmpl_norm_kernel(
    const float* __restrict__ piece, float* __restrict__ tn) {
    int b = blockIdx.x;
    const float* x = piece + b * NTEMPL;
    int tid = threadIdx.x;
    int wid = tid >> 6, lane = tid & 63;

    float v0 = (tid < NTEMPL) ? x[tid] : 0.f;
    float v1 = (tid + 256 < NTEMPL) ? x[tid + 256] : 0.f;

    __shared__ float sred[4];
    float s = v0 + v1;
    #pragma unroll
    for (int o = 32; o > 0; o >>= 1) s += __shfl_down(s, o, 64);
    if (lane == 0) sred[wid] = s;
    __syncthreads();
    float mean = (sred[0] + sred[1] + sred[2] + sred[3]) * (1.0f / NTEMPL);

    float d0 = (tid < NTEMPL) ? (v0 - mean) : 0.f;
    float d1 = (tid + 256 < NTEMPL) ? (v1 - mean) : 0.f;
    float q = d0 * d0 + d1 * d1;
    __syncthreads();
    #pragma unroll
    for (int o = 32; o > 0; o >>= 1) q += __shfl_down(q, o, 64);
    if (lane == 0) sred[wid] = q;
    __syncthreads();
    float var = (sred[0] + sred[1] + sred[2] + sred[3]) * (1.0f / (NTEMPL - 1));
    float stdv = sqrtf(var);
    if (stdv < EPSV) stdv = EPSV;
    float inv = 1.0f / stdv;

    float* o = tn + b * (HT * TPAD);
    for (int sIdx = tid; sIdx < HT * TPAD; sIdx += 256) {
        int i = sIdx / TPAD, j = sIdx % TPAD;
        o[sIdx] = (j < WT) ? (x[i * WT + j] - mean) * inv : 0.f;
    }
}

// ---------------- main-loop step, 4-row rolling window, compile-time phase --------
// Before step i: w[(i+e)&3] = bg row tr+i+e for e=0..3; ttf[i&1] = template row i.
// Order (dataflow-enforced): FMA out-row0 (slot P) -> prefetch bg row tr+i+4 into
// slot P (out0 is the only consumer of the oldest row) -> FMA out rows 1..3.
template<int P, bool LAST>
__device__ __forceinline__ void corr_step(
    int i, int tr, int xb,
    const float* __restrict__ tp,
    const float (*__restrict__ bg)[BP],
    float (&w)[4][TPAD], float (&ttf)[2][TPAD], float (&acc)[4][4])
{
    if (!LAST) {   // template row i+1 -> other ttf slot (uniform addr -> s_load/SGPR)
        const float4* tq = (const float4*)(tp + (i + 1) * TPAD);
        #pragma unroll
        for (int q = 0; q < 5; ++q) ((float4*)ttf[(P & 1) ^ 1])[q] = tq[q];
    }
    const float* tc = ttf[P & 1];
    #pragma unroll
    for (int j = 0; j < 17; ++j) {         // out row 0: bg row tr+i (slot P)
        float tv = tc[j];
        #pragma unroll
        for (int k = 0; k < 4; ++k) acc[0][k] = fmaf(tv, w[P][j + k], acc[0][k]);
    }
    if (!LAST) {   // prefetch bg row tr+i+4 into slot P (just freed)
        const float4* br = (const float4*)&bg[tr + i + 4][xb];
        #pragma unroll
        for (int q = 0; q < 5; ++q) ((float4*)w[P])[q] = br[q];
    }
    #pragma unroll
    for (int e = 1; e < 4; ++e) {          // out rows 1..3: slots (P+e)&3
        #pragma unroll
        for (int j = 0; j < 17; ++j) {
            float tv = tc[j];
            #pragma unroll
            for (int k = 0; k < 4; ++k)
                acc[e][k] = fmaf(tv, w[(P + e) & 3][j + k], acc[e][k]);
        }
    }
}

// ---- 16-row column-sum build: chains over bg rows [r0, r0+31] -> cb rows 0..15 ----
// Arithmetic identical to the former full c1/c2 build (fmaf init, incremental update).
template<bool SQ>
__device__ __forceinline__ void build_half(
    const float (*__restrict__ bg)[BP], float (*__restrict__ cb)[BP],
    int r0, int cc)
{
    float s = 0.f;
    #pragma unroll
    for (int i2 = 0; i2 < HT; ++i2) {
        float v = bg[r0 + i2][cc];
        if (SQ) s = fmaf(v, v, s); else s += v;
    }
    cb[0][cc] = s;
    for (int r = 1; r < 16; ++r) {
        float vn = bg[r0 + r + 16][cc], vo = bg[r0 + r - 1][cc];
        if (SQ) s += vn * vn - vo * vo; else s += vn - vo;
        cb[r][cc] = s;
    }
}

// ---- consume a half: 17-col window sums + sliding update into sv[4][4] ----
__device__ __forceinline__ void consume_half(
    const float (*__restrict__ cb)[BP], int row0, int xb, float (&sv)[4][4])
{
    #pragma unroll
    for (int e = 0; e < 4; ++e) {
        float cf[TPAD];
        const float4* a = (const float4*)&cb[row0 + e][xb];
        #pragma unroll
        for (int q = 0; q < 5; ++q) ((float4*)cf)[q] = a[q];
        float s = 0.f;
        #pragma unroll
        for (int j = 0; j < HT; ++j) s += cf[j];
        sv[e][0] = s;
        #pragma unroll
        for (int k = 1; k < 4; ++k) {
            s += cf[k - 1 + HT] - cf[k - 1];
            sv[e][k] = s;
        }
    }
}

// ---------------- kernel 2: correlation + per-tile softmax partials ----------------
// 4x4 micro-tile (one new bg row = 5 b128 feeds 272 FMAs) + small LDS: the former
// c1/c2[32][BP] buffers (36.9 KB) are replaced by one 16-row scratch cb[16][BP]
// (9.2 KB) filled in 4 short build passes after the main loop and consumed
// immediately into registers. LDS 36 928 B -> 4 blocks/CU = 16 waves/CU (r2 lesson:
// 2 blocks/CU left VALUBusy at 71%; occupancy was the limiter, not LDS traffic).
__global__ __launch_bounds__(256, 4) void corr_kernel(
    const float* __restrict__ bgg, const float* __restrict__ tn,
    float* __restrict__ partials) {
    int blk = blockIdx.x;
    int b = blk / NTILES;
    int t = blk % NTILES;
    int ty0 = (t / NTXT) * TY;
    int tx0 = (t % NTXT) * TX;
    const float* img = bgg + (size_t)b * HI * WI;
    const float* tp  = tn + b * (HT * TPAD);

    __shared__ float bg[BR][BP];   // 27648 B
    __shared__ float cb[16][BP];   //  9216 B (half-height column-sum scratch)
    __shared__ float redm[4], redl[4], redy[4], redx[4];

    int tid = threadIdx.x;
    int wid = tid >> 6, lane = tid & 63;

    // ---- stage bg tile (zero-filled OOB); 48 x 36 float4, linear across lanes ----
    for (int l = tid; l < BR * (BP / 4); l += 256) {
        int r = l / (BP / 4), c = (l % (BP / 4)) * 4;
        int iy = ty0 + r, ix = tx0 + c;
        float4 v = make_float4(0.f, 0.f, 0.f, 0.f);
        if (iy < HI && ix < WI) v = *(const float4*)(img + iy * WI + ix);
        *(float4*)&bg[r][c] = v;
    }
    __syncthreads();

    // ---- main loop: 4x4 micro-tile, rolling 4-row register window ----
    int tr = (tid >> 5) * 4;     // 0,4,...,28 (output row group)
    int xb = (tid & 31) * 4;     // 0..124
    float w[4][TPAD];
    float ttf[2][TPAD];
    float acc[4][4] = {};

    #pragma unroll
    for (int m = 0; m < 4; ++m) {
        const float4* br = (const float4*)&bg[tr + m][xb];
        #pragma unroll
        for (int q = 0; q < 5; ++q) ((float4*)w[m])[q] = br[q];
    }
    {
        const float4* t0 = (const float4*)tp;
        #pragma unroll
        for (int q = 0; q < 5; ++q) ((float4*)ttf[0])[q] = t0[q];
    }

    for (int i = 0; i < 16; i += 4) {
        corr_step<0, false>(i,     tr, xb, tp, bg, w, ttf, acc);
        corr_step<1, false>(i + 1, tr, xb, tp, bg, w, ttf, acc);
        corr_step<2, false>(i + 2, tr, xb, tp, bg, w, ttf, acc);
        corr_step<3, false>(i + 3, tr, xb, tp, bg, w, ttf, acc);
    }
    corr_step<0, true>(16, tr, xb, tp, bg, w, ttf, acc);

    // ---- window stats via 4 build/consume half-passes (bg read-only throughout,
    //      so the first build needs no barrier after the main loop) ----
    bool lowHalf = (tr < 16);
    int  row0    = lowHalf ? tr : (tr - 16);
    float s1v[4][4], s2v[4][4];

    if (tid < BP) build_half<false>(bg, cb, 0, tid);     // c1 rows 0..15
    __syncthreads();
    if (lowHalf) consume_half(cb, row0, xb, s1v);
    __syncthreads();
    if (tid < BP) build_half<false>(bg, cb, 16, tid);    // c1 rows 16..31
    __syncthreads();
    if (!lowHalf) consume_half(cb, row0, xb, s1v);
    __syncthreads();
    if (tid < BP) build_half<true>(bg, cb, 0, tid);      // c2 rows 0..15
    __syncthreads();
    if (lowHalf) consume_half(cb, row0, xb, s2v);
    __syncthreads();
    if (tid < BP) build_half<true>(bg, cb, 16, tid);     // c2 rows 16..31
    __syncthreads();
    if (!lowHalf) consume_half(cb, row0, xb, s2v);

    // ---- corr from acc and window stats (same op order as before) ----
    const float invn = 1.0f / NTEMPL;
    float corr[4][4];
    float m = -INFINITY;
    #pragma unroll
    for (int e = 0; e < 4; ++e) {
        int oy = ty0 + tr + e;
        #pragma unroll
        for (int k = 0; k < 4; ++k) {
            float mu = s1v[e][k] * invn;
            float var = s2v[e][k] * invn - mu * mu;
            if (var < EPSV) var = EPSV;
            float cv = acc[e][k] / sqrtf(var);
            int ox = tx0 + xb + k;
            if (oy < LH && ox < LW) m = fmaxf(m, cv);
            else cv = -INFINITY;
            corr[e][k] = cv;
        }
    }

    // ---- block max ----
    float mm = m;
    #pragma unroll
    for (int o = 32; o > 0; o >>= 1) mm = fmaxf(mm, __shfl_down(mm, o, 64));
    if (lane == 0) redm[wid] = mm;
    __syncthreads();
    float M = fmaxf(fmaxf(redm[0], redm[1]), fmaxf(redm[2], redm[3]));

    // ---- partial softmax sums relative to tile max ----
    float l = 0.f, sy = 0.f, sx = 0.f;
    #pragma unroll
    for (int e = 0; e < 4; ++e) {
        int oy = ty0 + tr + e;
        #pragma unroll
        for (int k = 0; k < 4; ++k) {
            float cv = corr[e][k];
            float ev = (cv == -INFINITY) ? 0.f : __expf((cv - M) * TEMP_INV);
            l += ev;
            sy = fmaf(ev, (float)oy, sy);
            sx = fmaf(ev, (float)(tx0 + xb + k), sx);
        }
    }
    #pragma unroll
    for (int o = 32; o > 0; o >>= 1) {
        l  += __shfl_down(l, o, 64);
        sy += __shfl_down(sy, o, 64);
        sx += __shfl_down(sx, o, 64);
    }
    if (lane == 0) { redl[wid] = l; redy[wid] = sy; redx[wid] = sx; }
    __syncthreads();
    if (tid == 0) {
        float* p = partials + (size_t)blk * 4;
        p[0] = M;
        p[1] = redl[0] + redl[1] + redl[2] + redl[3];
        p[2] = redy[0] + redy[1] + redy[2] + redy[3];
        p[3] = redx[0] + redx[1] + redx[2] + redx[3];
    }
}

// ---------------- kernel 3: per-batch merge of tile partials ----------------
__global__ __launch_bounds__(256) void reduce_kernel(
    const float* __restrict__ partials, float* __restrict__ out) {
    int b = blockIdx.x;
    int tid = threadIdx.x;
    int wid = tid >> 6, lane = tid & 63;

    float m = -INFINITY, l = 0.f, sy = 0.f, sx = 0.f;
    if (tid < NTILES) {
        const float* p = partials + (size_t)(b * NTILES + tid) * 4;
        m = p[0]; l = p[1]; sy = p[2]; sx = p[3];
    }
    __shared__ float rm[4], rl[4], ry[4], rx[4];
    float mm = m;
    #pragma unroll
    for (int o = 32; o > 0; o >>= 1) mm = fmaxf(mm, __shfl_down(mm, o, 64));
    if (lane == 0) rm[wid] = mm;
    __syncthreads();
    float M = fmaxf(fmaxf(rm[0], rm[1]), fmaxf(rm[2], rm[3]));

    float sc = (m == -INFINITY) ? 0.f : __expf((m - M) * TEMP_INV);
    l *= sc; sy *= sc; sx *= sc;
    #pragma unroll
    for (int o = 32; o > 0; o >>= 1) {
        l  += __shfl_down(l, o, 64);
        sy += __shfl_down(sy, o, 64);
        sx += __shfl_down(sx, o, 64);
    }
    if (lane == 0) { rl[wid] = l; ry[wid] = sy; rx[wid] = sx; }
    __syncthreads();
    if (tid == 0) {
        float L  = rl[0] + rl[1] + rl[2] + rl[3];
        float SY = ry[0] + ry[1] + ry[2] + ry[3];
        float SX = rx[0] + rx[1] + rx[2] + rx[3];
        out[b * 2 + 0] = SX / L - 183.5f;
        out[b * 2 + 1] = SY / L - 183.5f;
        out[2 * NB + b] = M;
    }
}

extern "C" void kernel_launch(void* const* d_in, const int* in_sizes, int n_in,
                              void* d_out, int out_size, void* d_ws, size_t ws_size,
                              hipStream_t stream) {
    const float* piece = (const float*)d_in[0];   // [256,1,17,17]
    const float* bgg   = (const float*)d_in[1];   // [256,1,384,384]
    float* out = (float*)d_out;                   // 512 offsets + 256 max_corr

    float* tn = (float*)d_ws;                     // 256 * 340 floats
    float* partials = tn + NB * HT * TPAD;        // 256*36*4 floats

    tmpl_norm_kernel<<<NB, 256, 0, stream>>>(piece, tn);
    corr_kernel<<<NB * NTILES, 256, 0, stream>>>(bgg, tn, partials);
    reduce_kernel<<<NB, 256, 0, stream>>>(partials, out);
}

// Round 5
// 472.903 us; speedup vs baseline: 1.5521x; 1.5521x over previous
//
#include <hip/hip_runtime.h>
#include <math.h>

#define NB 256       // batch
#define HT 17
#define WT 17
#define HI 384
#define WI 384
#define LH 368
#define LW 368
#define NTEMPL 289   // HT*WT
#define TPAD 20      // padded template row width (float4-friendly)
#define TY 32        // output tile rows per block
#define TX 128       // output tile cols per block
#define NTXT 3       // x tiles (3*128 = 384)
#define NTYT 12      // y tiles (12*32 = 384)
#define NTILES 36    // tiles per batch
#define BR 48        // bg tile rows (TY + 16)
#define BP 144       // bg/cb pitch: exactly 128+16 used. All wave LDS accesses are
                     // within-row 16-lane-contiguous -> pitch-independent conflict-free.
#define TEMP_INV 25.0f
#define EPSV 1e-6f

// ---------------- kernel 1: per-batch template normalization ----------------
__global__ __launch_bounds__(256) void tmpl_norm_kernel(
    const float* __restrict__ piece, float* __restrict__ tn) {
    int b = blockIdx.x;
    const float* x = piece + b * NTEMPL;
    int tid = threadIdx.x;
    int wid = tid >> 6, lane = tid & 63;

    float v0 = (tid < NTEMPL) ? x[tid] : 0.f;
    float v1 = (tid + 256 < NTEMPL) ? x[tid + 256] : 0.f;

    __shared__ float sred[4];
    float s = v0 + v1;
    #pragma unroll
    for (int o = 32; o > 0; o >>= 1) s += __shfl_down(s, o, 64);
    if (lane == 0) sred[wid] = s;
    __syncthreads();
    float mean = (sred[0] + sred[1] + sred[2] + sred[3]) * (1.0f / NTEMPL);

    float d0 = (tid < NTEMPL) ? (v0 - mean) : 0.f;
    float d1 = (tid + 256 < NTEMPL) ? (v1 - mean) : 0.f;
    float q = d0 * d0 + d1 * d1;
    __syncthreads();
    #pragma unroll
    for (int o = 32; o > 0; o >>= 1) q += __shfl_down(q, o, 64);
    if (lane == 0) sred[wid] = q;
    __syncthreads();
    float var = (sred[0] + sred[1] + sred[2] + sred[3]) * (1.0f / (NTEMPL - 1));
    float stdv = sqrtf(var);
    if (stdv < EPSV) stdv = EPSV;
    float inv = 1.0f / stdv;

    float* o = tn + b * (HT * TPAD);
    for (int sIdx = tid; sIdx < HT * TPAD; sIdx += 256) {
        int i = sIdx / TPAD, j = sIdx % TPAD;
        o[sIdx] = (j < WT) ? (x[i * WT + j] - mean) * inv : 0.f;
    }
}

// ---------------- main-loop step, 4-row rolling window, compile-time phase --------
// Before step i: w[(i+e)&3] = bg row tr+i+e for e=0..3. Template row i is loaded
// at step start into the SINGLE buffer tc (saves 20 VGPR vs double-buffer; exposed
// ~200cy L2 latency per step is covered by the other 2 waves/SIMD at 3 blocks/CU).
// Order (dataflow-enforced): load tc -> FMA out0 (slot P) -> prefetch bg row
// tr+i+4 into slot P (out0 is its only consumer) -> FMA out rows 1..3.
template<int P, bool LAST>
__device__ __forceinline__ void corr_step(
    int i, int tr, int xb,
    const float* __restrict__ tp,
    const float (*__restrict__ bg)[BP],
    float (&w)[4][TPAD], float (&tc)[TPAD], float (&acc)[4][4])
{
    const float4* tq = (const float4*)(tp + i * TPAD);
    #pragma unroll
    for (int q = 0; q < 5; ++q) ((float4*)tc)[q] = tq[q];
    #pragma unroll
    for (int j = 0; j < 17; ++j) {         // out row 0: bg row tr+i (slot P)
        float tv = tc[j];
        #pragma unroll
        for (int k = 0; k < 4; ++k) acc[0][k] = fmaf(tv, w[P][j + k], acc[0][k]);
    }
    if (!LAST) {   // prefetch bg row tr+i+4 into slot P (just freed)
        const float4* br = (const float4*)&bg[tr + i + 4][xb];
        #pragma unroll
        for (int q = 0; q < 5; ++q) ((float4*)w[P])[q] = br[q];
    }
    #pragma unroll
    for (int e = 1; e < 4; ++e) {          // out rows 1..3: slots (P+e)&3
        #pragma unroll
        for (int j = 0; j < 17; ++j) {
            float tv = tc[j];
            #pragma unroll
            for (int k = 0; k < 4; ++k)
                acc[e][k] = fmaf(tv, w[(P + e) & 3][j + k], acc[e][k]);
        }
    }
}

// ---- 16-row column-sum build: chains over bg rows [r0, r0+31] -> cb rows 0..15 ----
template<bool SQ>
__device__ __forceinline__ void build_half(
    const float (*__restrict__ bg)[BP], float (*__restrict__ cb)[BP],
    int r0, int cc)
{
    float s = 0.f;
    #pragma unroll
    for (int i2 = 0; i2 < HT; ++i2) {
        float v = bg[r0 + i2][cc];
        if (SQ) s = fmaf(v, v, s); else s += v;
    }
    cb[0][cc] = s;
    for (int r = 1; r < 16; ++r) {
        float vn = bg[r0 + r + 16][cc], vo = bg[r0 + r - 1][cc];
        if (SQ) s += vn * vn - vo * vo; else s += vn - vo;
        cb[r][cc] = s;
    }
}

// ---- consume a half: 17-col window sums + sliding update into sv[4][4] ----
__device__ __forceinline__ void consume_half(
    const float (*__restrict__ cb)[BP], int row0, int xb, float (&sv)[4][4])
{
    #pragma unroll
    for (int e = 0; e < 4; ++e) {
        float cf[TPAD];
        const float4* a = (const float4*)&cb[row0 + e][xb];
        #pragma unroll
        for (int q = 0; q < 5; ++q) ((float4*)cf)[q] = a[q];
        float s = 0.f;
        #pragma unroll
        for (int j = 0; j < HT; ++j) s += cf[j];
        sv[e][0] = s;
        #pragma unroll
        for (int k = 1; k < 4; ++k) {
            s += cf[k - 1 + HT] - cf[k - 1];
            sv[e][k] = s;
        }
    }
}

// ---------------- kernel 2: correlation + per-tile softmax partials ----------------
// Occupancy ladder (r0/r2/r4 measured): <=64 VGPR -> 4 blk/CU, <=85 -> 3, <=128 -> 2.
// r4 lesson: (256,4) pins cap at 64; the 4x4 window live set (~116) spilled to
// GB-scale scratch (WRITE_SIZE 1.25 GB). Here: single-buffer template (live ~116->
// ~96 ideal) + (256,3) cap 85 -> 3 blocks/CU, 12 waves. LDS 36 928 B (3x fits 160K).
__global__ __launch_bounds__(256, 3) void corr_kernel(
    const float* __restrict__ bgg, const float* __restrict__ tn,
    float* __restrict__ partials) {
    int blk = blockIdx.x;
    int b = blk / NTILES;
    int t = blk % NTILES;
    int ty0 = (t / NTXT) * TY;
    int tx0 = (t % NTXT) * TX;
    const float* img = bgg + (size_t)b * HI * WI;
    const float* tp  = tn + b * (HT * TPAD);

    __shared__ float bg[BR][BP];   // 27648 B
    __shared__ float cb[16][BP];   //  9216 B (half-height column-sum scratch)
    __shared__ float redm[4], redl[4], redy[4], redx[4];

    int tid = threadIdx.x;
    int wid = tid >> 6, lane = tid & 63;

    // ---- stage bg tile (zero-filled OOB); 48 x 36 float4, linear across lanes ----
    for (int l = tid; l < BR * (BP / 4); l += 256) {
        int r = l / (BP / 4), c = (l % (BP / 4)) * 4;
        int iy = ty0 + r, ix = tx0 + c;
        float4 v = make_float4(0.f, 0.f, 0.f, 0.f);
        if (iy < HI && ix < WI) v = *(const float4*)(img + iy * WI + ix);
        *(float4*)&bg[r][c] = v;
    }
    __syncthreads();

    // ---- main loop: 4x4 micro-tile, rolling 4-row register window ----
    int tr = (tid >> 5) * 4;     // 0,4,...,28 (output row group)
    int xb = (tid & 31) * 4;     // 0..124
    float w[4][TPAD];
    float tc[TPAD];
    float acc[4][4] = {};

    #pragma unroll
    for (int m = 0; m < 4; ++m) {
        const float4* br = (const float4*)&bg[tr + m][xb];
        #pragma unroll
        for (int q = 0; q < 5; ++q) ((float4*)w[m])[q] = br[q];
    }

    for (int i = 0; i < 16; i += 4) {
        corr_step<0, false>(i,     tr, xb, tp, bg, w, tc, acc);
        corr_step<1, false>(i + 1, tr, xb, tp, bg, w, tc, acc);
        corr_step<2, false>(i + 2, tr, xb, tp, bg, w, tc, acc);
        corr_step<3, false>(i + 3, tr, xb, tp, bg, w, tc, acc);
    }
    corr_step<0, true>(16, tr, xb, tp, bg, w, tc, acc);

    // ---- window stats via 4 build/consume half-passes (bg read-only throughout,
    //      so the first build needs no barrier after the main loop) ----
    bool lowHalf = (tr < 16);
    int  row0    = lowHalf ? tr : (tr - 16);
    float s1v[4][4], s2v[4][4];

    if (tid < BP) build_half<false>(bg, cb, 0, tid);     // c1 rows 0..15
    __syncthreads();
    if (lowHalf) consume_half(cb, row0, xb, s1v);
    __syncthreads();
    if (tid < BP) build_half<false>(bg, cb, 16, tid);    // c1 rows 16..31
    __syncthreads();
    if (!lowHalf) consume_half(cb, row0, xb, s1v);
    __syncthreads();
    if (tid < BP) build_half<true>(bg, cb, 0, tid);      // c2 rows 0..15
    __syncthreads();
    if (lowHalf) consume_half(cb, row0, xb, s2v);
    __syncthreads();
    if (tid < BP) build_half<true>(bg, cb, 16, tid);     // c2 rows 16..31
    __syncthreads();
    if (!lowHalf) consume_half(cb, row0, xb, s2v);

    // ---- corr from acc and window stats (same op order as before) ----
    const float invn = 1.0f / NTEMPL;
    float corr[4][4];
    float m = -INFINITY;
    #pragma unroll
    for (int e = 0; e < 4; ++e) {
        int oy = ty0 + tr + e;
        #pragma unroll
        for (int k = 0; k < 4; ++k) {
            float mu = s1v[e][k] * invn;
            float var = s2v[e][k] * invn - mu * mu;
            if (var < EPSV) var = EPSV;
            float cv = acc[e][k] / sqrtf(var);
            int ox = tx0 + xb + k;
            if (oy < LH && ox < LW) m = fmaxf(m, cv);
            else cv = -INFINITY;
            corr[e][k] = cv;
        }
    }

    // ---- block max ----
    float mm = m;
    #pragma unroll
    for (int o = 32; o > 0; o >>= 1) mm = fmaxf(mm, __shfl_down(mm, o, 64));
    if (lane == 0) redm[wid] = mm;
    __syncthreads();
    float M = fmaxf(fmaxf(redm[0], redm[1]), fmaxf(redm[2], redm[3]));

    // ---- partial softmax sums relative to tile max ----
    float l = 0.f, sy = 0.f, sx = 0.f;
    #pragma unroll
    for (int e = 0; e < 4; ++e) {
        int oy = ty0 + tr + e;
        #pragma unroll
        for (int k = 0; k < 4; ++k) {
            float cv = corr[e][k];
            float ev = (cv == -INFINITY) ? 0.f : __expf((cv - M) * TEMP_INV);
            l += ev;
            sy = fmaf(ev, (float)oy, sy);
            sx = fmaf(ev, (float)(tx0 + xb + k), sx);
        }
    }
    #pragma unroll
    for (int o = 32; o > 0; o >>= 1) {
        l  += __shfl_down(l, o, 64);
        sy += __shfl_down(sy, o, 64);
        sx += __shfl_down(sx, o, 64);
    }
    if (lane == 0) { redl[wid] = l; redy[wid] = sy; redx[wid] = sx; }
    __syncthreads();
    if (tid == 0) {
        float* p = partials + (size_t)blk * 4;
        p[0] = M;
        p[1] = redl[0] + redl[1] + redl[2] + redl[3];
        p[2] = redy[0] + redy[1] + redy[2] + redy[3];
        p[3] = redx[0] + redx[1] + redx[2] + redx[3];
    }
}

// ---------------- kernel 3: per-batch merge of tile partials ----------------
__global__ __launch_bounds__(256) void reduce_kernel(
    const float* __restrict__ partials, float* __restrict__ out) {
    int b = blockIdx.x;
    int tid = threadIdx.x;
    int wid = tid >> 6, lane = tid & 63;

    float m = -INFINITY, l = 0.f, sy = 0.f, sx = 0.f;
    if (tid < NTILES) {
        const float* p = partials + (size_t)(b * NTILES + tid) * 4;
        m = p[0]; l = p[1]; sy = p[2]; sx = p[3];
    }
    __shared__ float rm[4], rl[4], ry[4], rx[4];
    float mm = m;
    #pragma unroll
    for (int o = 32; o > 0; o >>= 1) mm = fmaxf(mm, __shfl_down(mm, o, 64));
    if (lane == 0) rm[wid] = mm;
    __syncthreads();
    float M = fmaxf(fmaxf(rm[0], rm[1]), fmaxf(rm[2], rm[3]));

    float sc = (m == -INFINITY) ? 0.f : __expf((m - M) * TEMP_INV);
    l *= sc; sy *= sc; sx *= sc;
    #pragma unroll
    for (int o = 32; o > 0; o >>= 1) {
        l  += __shfl_down(l, o, 64);
        sy += __shfl_down(sy, o, 64);
        sx += __shfl_down(sx, o, 64);
    }
    if (lane == 0) { rl[wid] = l; ry[wid] = sy; rx[wid] = sx; }
    __syncthreads();
    if (tid == 0) {
        float L  = rl[0] + rl[1] + rl[2] + rl[3];
        float SY = ry[0] + ry[1] + ry[2] + ry[3];
        float SX = rx[0] + rx[1] + rx[2] + rx[3];
        out[b * 2 + 0] = SX / L - 183.5f;
        out[b * 2 + 1] = SY / L - 183.5f;
        out[2 * NB + b] = M;
    }
}

extern "C" void kernel_launch(void* const* d_in, const int* in_sizes, int n_in,
                              void* d_out, int out_size, void* d_ws, size_t ws_size,
                              hipStream_t stream) {
    const float* piece = (const float*)d_in[0];   // [256,1,17,17]
    const float* bgg   = (const float*)d_in[1];   // [256,1,384,384]
    float* out = (float*)d_out;                   // 512 offsets + 256 max_corr

    float* tn = (float*)d_ws;                     // 256 * 340 floats
    float* partials = tn + NB * HT * TPAD;        // 256*36*4 floats

    tmpl_norm_kernel<<<NB, 256, 0, stream>>>(piece, tn);
    corr_kernel<<<NB * NTILES, 256, 0, stream>>>(bgg, tn, partials);
    reduce_kernel<<<NB, 256, 0, stream>>>(partials, out);
}